// Round 4
// baseline (1783.636 us; speedup 1.0000x reference)
//
#include <hip/hip_runtime.h>
#include <hip/hip_bf16.h>

// Problem constants
#define Hdim 1024
#define Nb   2048
#define Lsteps 48

// GEMM tile geometry: BM n-rows x BJ j-cols (x4 gates = 128 B-rows), BK=64.
// Staging traffic/step = (1/BJ + 4/BM) * 2048*1024*2048 B:
//   128x32 (old, 512 blk) = 256 MB; 256x32 (this, 256 blk) = 192 MB (-25%).
#define BM 256
#define BROWS 128          // B-tile rows = 4 gates * 32 j
#define NT 16              // K-tiles (1024/64)
#define DEPTH 3            // pipeline depth (triple buffer)

typedef unsigned short ushort_t;
typedef short bf16x8 __attribute__((ext_vector_type(8)));   // 8 bf16 (4 VGPRs)
typedef float f32x4 __attribute__((ext_vector_type(4)));    // 4 fp32 accum

typedef __attribute__((address_space(3))) unsigned int lds_u32;
typedef const __attribute__((address_space(1))) unsigned int glb_u32;

__device__ __forceinline__ void gll16(const void* g, void* l) {
    __builtin_amdgcn_global_load_lds((glb_u32*)g, (lds_u32*)l, 16, 0, 0);
}

// RTN-even fp32 -> bf16 bits
__device__ __forceinline__ ushort_t f2bf(float x) {
    unsigned u = __builtin_bit_cast(unsigned, x);
    unsigned r = u + 0x7fffu + ((u >> 16) & 1u);
    return (ushort_t)(r >> 16);
}

__device__ __forceinline__ float frcp(float x) { return __builtin_amdgcn_rcpf(x); }
__device__ __forceinline__ float fsigmoid(float x) { return frcp(1.0f + __expf(-x)); }
__device__ __forceinline__ float ftanh(float x) {
    float xm = fminf(fmaxf(x, -15.0f), 15.0f);
    float e = __expf(2.0f * xm);
    return (e - 1.0f) * frcp(e + 1.0f);
}

__device__ __forceinline__ f32x4 mfma16(bf16x8 a, bf16x8 b, f32x4 c) {
    return __builtin_amdgcn_mfma_f32_16x16x32_bf16(a, b, c, 0, 0, 0);
}

#define VMCNT12  asm volatile("s_waitcnt vmcnt(12)" ::: "memory")
#define VMCNT6   asm volatile("s_waitcnt vmcnt(6)"  ::: "memory")
#define VMCNT0   asm volatile("s_waitcnt vmcnt(0)"  ::: "memory")
#define LGKMCNT0 asm volatile("s_waitcnt lgkmcnt(0)" ::: "memory")

// ---------------------------------------------------------------------------
// Prep kernels
// ---------------------------------------------------------------------------
__global__ __launch_bounds__(256) void prep_w(const float* __restrict__ W,
                                              ushort_t* __restrict__ Wb) {
    int i = blockIdx.x * 256 + threadIdx.x;
    Wb[i] = f2bf(W[i]);
}

__global__ __launch_bounds__(256) void prep_h(const float* __restrict__ h_in,
                                              ushort_t* __restrict__ h0,
                                              const float* __restrict__ b_ih,
                                              const float* __restrict__ b_hh,
                                              float* __restrict__ bias) {
    int i = blockIdx.x * 256 + threadIdx.x;
    h0[i] = f2bf(h_in[i]);
    if (i < 4 * Hdim) bias[i] = b_ih[i] + b_hh[i];
}

// ---------------------------------------------------------------------------
// Fused step: 256 blocks x 512 threads (8 waves, 1 block/CU), tile 256n x 32j
// x 4 gates, BK=64, DEPTH-3 counted-vmcnt pipeline.
// Wave (wr = wid>>1 in 0..3, wc = wid&1): output 64n x (4g x 16j) — identical
// per-wave fragment/epilogue structure to the verified 128-tile kernel.
// LDS: 3 x (A 32 KB + B 16 KB) = 144 KB dynamic (static cap is 64 KB).
// cst prefetched into registers BEFORE the K-loop (1 blk/CU has no partner
// block to hide epilogue load latency). Extra outstanding loads can only make
// counted vmcnt waits MORE conservative (in-order retirement), never unsafe.
//
// XCD remap (256 blocks = 8 xcd x 32 slots): per-XCD working set =
// 4 nb x 256 h-rows (2 MB) + 8 jb x 128 W-rows (2 MB) -> fits 4 MB L2.
// ---------------------------------------------------------------------------
__global__ __launch_bounds__(512, 2) void lstm_step(
    const ushort_t* __restrict__ hsrc,   // [Nb][Hdim] bf16 bits
    ushort_t* __restrict__ hdst,         // [Nb][Hdim] bf16 bits
    const ushort_t* __restrict__ Wb,     // [4*Hdim][Hdim] bf16 bits
    const float* __restrict__ bias,      // [4*Hdim]
    float* __restrict__ cst,             // [Nb][Hdim] fp32 cell state
    float* __restrict__ tmp)             // [Nb][Hdim] fp32 h output slot
{
    extern __shared__ __align__(16) ushort_t smem[];
    ushort_t* As = smem;                         // [3][BM*64]    96 KB
    ushort_t* Bs = smem + DEPTH * (BM * 64);     // [3][BROWS*64] 48 KB

    const int tid  = threadIdx.x;
    const int lane = tid & 63;
    const int wid  = tid >> 6;            // 0..7
    const int wr   = wid >> 1;            // n quarter (0..3)
    const int wc   = wid & 1;             // j half (0..1)

    // XCD-aware remap: p%8 = XCD, 32 slots per XCD.
    const int p    = blockIdx.x;
    const int xcd  = p & 7;
    const int slot = p >> 3;              // 0..31
    const int jb   = (xcd >> 1) * 8 + (slot & 7);   // 0..31
    const int nb   = (xcd & 1) * 4 + (slot >> 3);   // 0..7
    const int n0   = nb * BM;
    const int j0   = jb * 32;

    // epilogue cell indices (fixed per thread)
    const int lr   = lane & 15;
    const int q4   = (lane >> 4) * 4;
    const int j    = j0 + wc * 16 + lr;

    // ---- prefetch cell state + bias into registers (hidden under K-loop) ----
    float cpre[16];
#pragma unroll
    for (int ri = 0; ri < 4; ++ri)
#pragma unroll
        for (int q = 0; q < 4; ++q)
            cpre[ri * 4 + q] = cst[(size_t)(n0 + wr * 64 + ri * 16 + q4 + q) * Hdim + j];
    const float bi = bias[j];
    const float bf = bias[Hdim + j];
    const float bg = bias[2 * Hdim + j];
    const float bo = bias[3 * Hdim + j];

    f32x4 acc[4][4];
#pragma unroll
    for (int g = 0; g < 4; ++g)
#pragma unroll
        for (int ri = 0; ri < 4; ++ri)
            acc[g][ri] = (f32x4){0.f, 0.f, 0.f, 0.f};

    // staging geometry: per gll instr, 8 rows x 128 B; lane -> (row, chunk)
    const int srow8  = lane >> 3;                      // 0..7
    const int schunk = (lane & 7) ^ srow8;             // swizzled 16B chunk
    const int choff  = schunk * 8;

    // A: wave stages rows [wid*32, wid*32+32) of the 256-row h-tile (4 gll)
    const ushort_t* aGlob = hsrc + (size_t)(n0 + wid * 32 + srow8) * Hdim + choff;
    // B: wave stages B-tile rows [wid*16, wid*16+16) (2 gll); B-tile row u
    // holds W row (u>>5)*1024 + j0 + (u&31)
    const ushort_t* bGlob = Wb + (size_t)((wid >> 1) * Hdim + j0 + (wid & 1) * 16 + srow8) * Hdim + choff;

    const int rsw  = lr & 7;
    const int cq   = lane >> 4;

    auto STAGE = [&](int buf, int it) {
        const int k0 = it * 64;
#pragma unroll
        for (int ii = 0; ii < 4; ++ii)
            gll16(aGlob + (size_t)ii * 8 * Hdim + k0,
                  &As[buf * (BM * 64) + (wid * 32 + ii * 8) * 64]);
#pragma unroll
        for (int ii = 0; ii < 2; ++ii)
            gll16(bGlob + (size_t)ii * 8 * Hdim + k0,
                  &Bs[buf * (BROWS * 64) + (wid * 16 + ii * 8) * 64]);
    };

    auto COMPUTE = [&](int buf) {
#pragma unroll
        for (int kh = 0; kh < 2; ++kh) {
            const int ch = ((cq + kh * 4) ^ rsw) * 8;
            bf16x8 af[4], bfr[4];
#pragma unroll
            for (int ri = 0; ri < 4; ++ri) {
                int row = wr * 64 + ri * 16 + lr;
                af[ri] = *(const bf16x8*)&As[buf * (BM * 64) + row * 64 + ch];
            }
#pragma unroll
            for (int g = 0; g < 4; ++g) {
                int u = g * 32 + wc * 16 + lr;
                bfr[g] = *(const bf16x8*)&Bs[buf * (BROWS * 64) + u * 64 + ch];
            }
#pragma unroll
            for (int g = 0; g < 4; ++g)
#pragma unroll
                for (int ri = 0; ri < 4; ++ri)
                    acc[g][ri] = mfma16(af[ri], bfr[g], acc[g][ri]);
        }
    };

    // ---- depth-3 counted-vmcnt pipeline, 16 K-tiles; tile k lives in buf k%3
    STAGE(0, 0); STAGE(1, 1); STAGE(2, 2);   // 18 gll in flight/wave
    int cur = 0;
#pragma unroll 1
    for (int t = 0; t < NT; ++t) {
        if (t <= NT - 3)      { VMCNT12; }   // 18 in flight -> oldest 6 landed
        else if (t == NT - 2) { VMCNT6;  }   // 12 in flight
        else                  { VMCNT0;  }   // 6 in flight
        __builtin_amdgcn_s_barrier();
        __builtin_amdgcn_s_setprio(1);
        COMPUTE(cur);
        __builtin_amdgcn_s_setprio(0);
        if (t <= NT - 4) {
            LGKMCNT0;                        // all reads of buf[cur] retired
            __builtin_amdgcn_s_barrier();    // -> safe to overwrite
            STAGE(cur, t + 3);               // (t+3)%3 == cur
        }
        cur = (cur == 2) ? 0 : cur + 1;
    }

    // ---- Epilogue: C/D layout col=lane&15, row=(lane>>4)*4+reg ----
#pragma unroll
    for (int ri = 0; ri < 4; ++ri)
#pragma unroll
        for (int q = 0; q < 4; ++q) {
            int n = n0 + wr * 64 + ri * 16 + q4 + q;
            float gi = fsigmoid(acc[0][ri][q] + bi);
            float gf = fsigmoid(acc[1][ri][q] + bf);
            float gg = ftanh(acc[2][ri][q] + bg);
            float go = fsigmoid(acc[3][ri][q] + bo);
            size_t idx = (size_t)n * Hdim + j;
            float cn = gf * cpre[ri * 4 + q] + gi * gg;
            cst[idx] = cn;
            float hv = go * ftanh(cn);
            hdst[idx] = f2bf(hv);
            tmp[idx] = hv;
        }
}

// ---------------------------------------------------------------------------
// Flush: tmp[16][Nb][Hdim] -> out[n][j][t0 : t0+16]  (full 64B granules)
// ---------------------------------------------------------------------------
__global__ __launch_bounds__(256) void flush16(const float* __restrict__ tmp,
                                               float* __restrict__ out, int t0) {
    int idx = blockIdx.x * 256 + threadIdx.x;
    float v[16];
#pragma unroll
    for (int s = 0; s < 16; ++s)
        v[s] = tmp[(size_t)s * (Nb * Hdim) + idx];
    float4* dst = (float4*)(out + (size_t)idx * Lsteps + t0);
#pragma unroll
    for (int s = 0; s < 4; ++s)
        dst[s] = make_float4(v[4 * s], v[4 * s + 1], v[4 * s + 2], v[4 * s + 3]);
}

// ---------------------------------------------------------------------------
extern "C" void kernel_launch(void* const* d_in, const int* in_sizes, int n_in,
                              void* d_out, int out_size, void* d_ws, size_t ws_size,
                              hipStream_t stream) {
    const float* h_in = (const float*)d_in[0];
    const float* W    = (const float*)d_in[1];
    const float* b_ih = (const float*)d_in[2];
    const float* b_hh = (const float*)d_in[3];
    float* out = (float*)d_out;

    char* ws = (char*)d_ws;
    ushort_t* Wb   = (ushort_t*)(ws);
    ushort_t* h0   = (ushort_t*)(ws + 8388608);
    ushort_t* h1   = (ushort_t*)(ws + 12582912);
    float*    cst  = (float*)(ws + 16777216);
    float*    bias = (float*)(ws + 25165824);
    float*    tmp16= (float*)(ws + 25182208);

    // 144 KB dynamic LDS (> 64 KB static cap) — raise the attribute once.
    static bool attr_done = false;
    if (!attr_done) {
        hipFuncSetAttribute((const void*)lstm_step,
                            hipFuncAttributeMaxDynamicSharedMemorySize,
                            DEPTH * (BM * 64 + BROWS * 64) * (int)sizeof(ushort_t));
        attr_done = true;
    }
    const int smem_bytes = DEPTH * (BM * 64 + BROWS * 64) * (int)sizeof(ushort_t);

    hipMemsetAsync(cst, 0, (size_t)Nb * Hdim * sizeof(float), stream);

    prep_w<<<(4 * Hdim * Hdim) / 256, 256, 0, stream>>>(W, Wb);
    prep_h<<<(Nb * Hdim) / 256, 256, 0, stream>>>(h_in, h0, b_ih, b_hh, bias);

    for (int t = 0; t < Lsteps; ++t) {
        const ushort_t* hs = (t & 1) ? h1 : h0;
        ushort_t*       hd = (t & 1) ? h0 : h1;
        float* tslot = tmp16 + (size_t)(t & 15) * (Nb * Hdim);
        lstm_step<<<256, 512, smem_bytes, stream>>>(hs, hd, Wb, bias, cst, tslot);
        if ((t & 15) == 15) {
            flush16<<<(Nb * Hdim) / 256, 256, 0, stream>>>(tmp16, out, t - 15);
        }
    }
}